// Round 19
// baseline (213.094 us; speedup 1.0000x reference)
//
#include <hip/hip_runtime.h>
#include <stdint.h>

#define DEV __device__ __forceinline__

typedef unsigned short u16;
typedef __bf16 bf16x8 __attribute__((ext_vector_type(8)));
typedef float  f32x4  __attribute__((ext_vector_type(4)));
typedef unsigned short u16x8 __attribute__((ext_vector_type(8)));
typedef unsigned short u16x4 __attribute__((ext_vector_type(4)));
typedef float  fvec4  __attribute__((ext_vector_type(4)));

constexpr int Sz   = 1024;  // sequence length
constexpr int Dm   = 1024;  // model dim
constexpr int HDm  = 64;    // head size
constexpr int NREL = 512;
constexpr int Mrows = 8192; // B*S
constexpr int KV   = 32;    // KV tile rows
constexpr float SCQ = 0.125f * 1.44269504f;  // folded into Q projection

DEV u16 f2bf(float f) { return __builtin_bit_cast(u16, (__bf16)f); }
DEV float bf2f(u16 h) { return __builtin_bit_cast(float, (uint32_t)h << 16); }
DEV f32x4 mfma16(bf16x8 a, bf16x8 b, f32x4 c) {
  return __builtin_amdgcn_mfma_f32_16x16x32_bf16(a, b, c, 0, 0, 0);
}
DEV float ex2(float x) {  // v_exp_f32 computes 2^x
  float r;
  asm("v_exp_f32 %0, %1" : "=v"(r) : "v"(x));
  return r;
}

// hardware transpose read. Lane l fetches 8B at its OWN addr; fixed cross-lane
// permute within each 16-lane group delivers elem j = region[(l&15) + 16j].
DEV u16x4 tr0(const u16* p) {
  u16x4 d;
  asm volatile("ds_read_b64_tr_b16 %0, %1"
               : "=v"(d)
               : "v"((const __attribute__((address_space(3))) u16*)p));
  return d;
}
DEV u16x4 tr512(const u16* p) {  // +512 bytes = next 4-row (j) subtile
  u16x4 d;
  asm volatile("ds_read_b64_tr_b16 %0, %1 offset:512"
               : "=v"(d)
               : "v"((const __attribute__((address_space(3))) u16*)p));
  return d;
}
DEV bf16x8 mk8(u16x4 a, u16x4 b) {
  u16x8 r;
  r[0] = a[0]; r[1] = a[1]; r[2] = a[2]; r[3] = a[3];
  r[4] = b[0]; r[5] = b[1]; r[6] = b[2]; r[7] = b[3];
  return __builtin_bit_cast(bf16x8, r);
}
DEV void gload(const u16* src, u16* dst) {
  __builtin_amdgcn_global_load_lds(
      (const __attribute__((address_space(1))) void*)src,
      (__attribute__((address_space(3))) void*)dst, 16, 0, 0);
}

// ---------------- merged weight/pos fp32 -> bf16 conversion ----------------
__global__ __launch_bounds__(256) void cvtw_kernel(const float* __restrict__ w0,
                                                   const float* __restrict__ w1,
                                                   const float* __restrict__ w2,
                                                   const float* __restrict__ w3,
                                                   const float* __restrict__ ps,
                                                   u16* __restrict__ o0,
                                                   u16* __restrict__ o1,
                                                   u16* __restrict__ o2,
                                                   u16* __restrict__ o3,
                                                   u16* __restrict__ op) {
  const int bid = blockIdx.x;
  const float* in;
  u16* out;
  int local;
  if (bid < 4096) {
    const int s = bid >> 10;
    in = s == 0 ? w0 : s == 1 ? w1 : s == 2 ? w2 : w3;
    out = s == 0 ? o0 : s == 1 ? o1 : s == 2 ? o2 : o3;
    local = bid & 1023;
  } else {
    in = ps; out = op; local = bid - 4096;
  }
  size_t i = (size_t)local * 256 + threadIdx.x;
  fvec4 v = *(const fvec4*)(in + i * 4);
  u16x4 o;
  o[0] = f2bf(v[0]); o[1] = f2bf(v[1]); o[2] = f2bf(v[2]); o[3] = f2bf(v[3]);
  *(u16x4*)(out + i * 4) = o;
}

// ---------------- GEMM bodies: C[m,n] = scale*(sum_k A*Bw + bias) ----------
template<bool OUT_BF16>
DEV void gemm_epilogue(const float* bias, void* Cout, int m0, int n0,
                       int wr, int wc, int lr, int lg, f32x4 acc[4][4],
                       float scale) {
  #pragma unroll
  for (int m = 0; m < 4; ++m) {
    const int grow = m0 + wr + m * 16 + lr;
    #pragma unroll
    for (int n = 0; n < 4; ++n) {
      const int gcol = n0 + wc + n * 16 + lg * 4;
      fvec4 bb = *(const fvec4*)&bias[gcol];
      if (OUT_BF16) {
        u16x4 w;
        #pragma unroll
        for (int r = 0; r < 4; ++r) w[r] = f2bf((acc[m][n][r] + bb[r]) * scale);
        *(u16x4*)&((u16*)Cout)[(size_t)grow * Dm + gcol] = w;
      } else {
        fvec4 w;
        #pragma unroll
        for (int r = 0; r < 4; ++r) w[r] = (acc[m][n][r] + bb[r]) * scale;
        *(fvec4*)&((float*)Cout)[(size_t)grow * Dm + gcol] = w;
      }
    }
  }
}

DEV void gemm_compute(const u16* Ab, const u16* Bb, int wr, int wc,
                      int lr, int lg, f32x4 (&acc)[4][4]) {
  #pragma unroll
  for (int kk = 0; kk < 2; ++kk) {
    bf16x8 af[4], bf_[4];
    #pragma unroll
    for (int m = 0; m < 4; ++m)
      af[m] = *(const bf16x8*)&Ab[(wr + m * 16 + lr) * 64 + (((kk * 4 + lg) ^ (lr & 7)) * 8)];
    #pragma unroll
    for (int n = 0; n < 4; ++n)
      bf_[n] = *(const bf16x8*)&Bb[(wc + n * 16 + lr) * 64 + (((kk * 4 + lg) ^ (lr & 7)) * 8)];
    __builtin_amdgcn_s_setprio(1);
    #pragma unroll
    for (int m = 0; m < 4; ++m)
      #pragma unroll
      for (int n = 0; n < 4; ++n)
        acc[m][n] = mfma16(bf_[n], af[m], acc[m][n]);  // swapped roles
    __builtin_amdgcn_s_setprio(0);
  }
}

// bf16-A body: both operands via global_load_lds, ONE barrier per tile.
template<bool OUT_BF16>
DEV void gemm_body16(const u16* __restrict__ A, const u16* __restrict__ Bw,
                     const float* __restrict__ bias, void* __restrict__ Cout,
                     int m0, int n0, u16* As, u16* Bs) {
  const int tid = threadIdx.x;
  const int wave = tid >> 6, lane = tid & 63;
  const int lr = lane & 15, lg = lane >> 4;
  const int wr = (wave >> 1) * 64, wc = (wave & 1) * 64;

  auto issue = [&](int t) {
    const int k0 = t * 64;
    u16* Ad = As + (t & 1) * (128 * 64);
    u16* Bd = Bs + (t & 1) * (128 * 64);
    #pragma unroll
    for (int it = 0; it < 4; ++it) {
      int chunk = it * 256 + tid;
      int row = chunk >> 3, c16 = chunk & 7;
      gload(Bw + (size_t)(n0 + row) * Dm + k0 + ((c16 ^ (row & 7)) * 8),
            Bd + (it * 256 + wave * 64) * 8);
      gload(A + (size_t)(m0 + row) * Dm + k0 + ((c16 ^ (row & 7)) * 8),
            Ad + (it * 256 + wave * 64) * 8);
    }
  };

  issue(0);
  f32x4 acc[4][4] = {};
  for (int t = 0; t < 16; ++t) {
    __builtin_amdgcn_s_barrier();
    if (t < 15) {
      issue(t + 1);
      asm volatile("s_waitcnt vmcnt(8)" ::: "memory");
    } else {
      asm volatile("s_waitcnt vmcnt(0)" ::: "memory");
    }
    gemm_compute(As + (t & 1) * (128 * 64), Bs + (t & 1) * (128 * 64),
                 wr, wc, lr, lg, acc);
  }
  gemm_epilogue<OUT_BF16>(bias, Cout, m0, n0, wr, wc, lr, lg, acc, 1.0f);
}

// fp32-A body (round-17 proven): 48 KB LDS. A reg-staged 2-deep into SINGLE-
// buffered 16 KB A-LDS; B gload_lds DOUBLE-buffered 32 KB, 1-deep prefetch.
// Head-wait vmcnt(8) drains {A(t), B(t)} while A(t+2)'s 8 stay in flight.
template<bool OUT_BF16>
DEV void gemm_body32(const float* __restrict__ A, const u16* __restrict__ Bw,
                     const float* __restrict__ bias, void* __restrict__ Cout,
                     int m0, int n0, u16* As, u16* Bs, float scale) {
  const int tid = threadIdx.x;
  const int wave = tid >> 6, lane = tid & 63;
  const int lr = lane & 15, lg = lane >> 4;
  const int wr = (wave >> 1) * 64, wc = (wave & 1) * 64;

  auto loadA = [&](int t, fvec4 (&arr)[4][2]) {
    const int k0 = t * 64;
    #pragma unroll
    for (int it = 0; it < 4; ++it) {
      int chunk = it * 256 + tid;
      int rw = chunk >> 3, cc = chunk & 7;
      const float* src = A + (size_t)(m0 + rw) * Dm + k0 + cc * 8;
      arr[it][0] = *(const fvec4*)src;
      arr[it][1] = *(const fvec4*)(src + 4);
    }
  };
  auto issueB = [&](int t) {
    const int k0 = t * 64;
    u16* Bd = Bs + (t & 1) * (128 * 64);
    #pragma unroll
    for (int it = 0; it < 4; ++it) {
      int chunk = it * 256 + tid;
      int rw = chunk >> 3, cc = chunk & 7;
      gload(Bw + (size_t)(n0 + rw) * Dm + k0 + ((cc ^ (rw & 7)) * 8),
            Bd + (it * 256 + wave * 64) * 8);
    }
  };
  auto writeA = [&](fvec4 (&arr)[4][2]) {
    #pragma unroll
    for (int it = 0; it < 4; ++it) {
      int chunk = it * 256 + tid;
      int rw = chunk >> 3, cc = chunk & 7;
      u16x8 v;
      #pragma unroll
      for (int e = 0; e < 4; ++e) { v[e] = f2bf(arr[it][0][e]); v[e + 4] = f2bf(arr[it][1][e]); }
      *(u16x8*)&As[rw * 64 + ((cc ^ (rw & 7)) * 8)] = v;
    }
  };

  fvec4 ar0[4][2], ar1[4][2];
  loadA(0, ar0);
  __builtin_amdgcn_sched_barrier(0);
  issueB(0);
  __builtin_amdgcn_sched_barrier(0);
  loadA(1, ar1);
  __builtin_amdgcn_sched_barrier(0);

  f32x4 acc[4][4] = {};
  auto step = [&](int t, fvec4 (&arr)[4][2]) {
    // head: drain {A(t), B(t)}; A(t+1) (8 ops) stays in flight
    if (t < 15) {
      asm volatile("s_waitcnt vmcnt(8)" ::: "memory");
    } else {
      asm volatile("s_waitcnt vmcnt(0)" ::: "memory");
    }
    __builtin_amdgcn_sched_barrier(0);
    writeA(arr);  // A(t) -> single-buffer LDS (post-barrier2(t-1): race-free)
    __builtin_amdgcn_sched_barrier(0);
    if (t < 15) {
      issueB(t + 1);                      // B first (order matters for vmcnt)
      __builtin_amdgcn_sched_barrier(0);
    }
    if (t < 14) {
      loadA(t + 2, arr);                  // reuse same named set (parity)
      __builtin_amdgcn_sched_barrier(0);
    }
    asm volatile("s_waitcnt lgkmcnt(0)" ::: "memory");   // A ds_writes done
    __builtin_amdgcn_s_barrier();
    gemm_compute(As, Bs + (t & 1) * (128 * 64), wr, wc, lr, lg, acc);
    __builtin_amdgcn_s_barrier();
  };
  for (int t = 0; t < 16; t += 2) {
    step(t, ar0);
    step(t + 1, ar1);
  }
  gemm_epilogue<OUT_BF16>(bias, Cout, m0, n0, wr, wc, lr, lg, acc, scale);
}

// output projection GEMM (bf16 A), XCD m-panel clustering.
template<bool OUT_BF16>
__global__ __launch_bounds__(256) void gemm1_kernel(const u16* __restrict__ A,
                                                    const u16* __restrict__ Bw,
                                                    const float* __restrict__ bias,
                                                    void* __restrict__ Cout) {
  __shared__ u16 As[2 * 128 * 64];
  __shared__ u16 Bs[2 * 128 * 64];
  const int r = blockIdx.x;
  const int xcd = r & 7, loc = r >> 3;
  const int m0 = (xcd * 8 + (loc & 7)) * 128;
  const int n0 = (loc >> 3) * 128;
  gemm_body16<OUT_BF16>(A, Bw, bias, Cout, m0, n0, As, Bs);
}

// merged Q/K/V projections, fp32 inputs with fused convert (one dispatch).
// Q (seg 0) is pre-scaled by SCQ -> attn softmax needs no mul.
__global__ __launch_bounds__(256) void gemm3_kernel(
    const float* __restrict__ Xq, const float* __restrict__ Xk, const float* __restrict__ Xv,
    const u16* __restrict__ Wq, const u16* __restrict__ Wk, const u16* __restrict__ Wv,
    const float* __restrict__ bq, const float* __restrict__ bk, const float* __restrict__ bv,
    u16* __restrict__ Cq, u16* __restrict__ Ck, u16* __restrict__ Cv) {
  __shared__ u16 As[128 * 64];
  __shared__ u16 Bs[2 * 128 * 64];
  const int flat = blockIdx.x;
  const int seg = flat >> 9;
  const int r = flat & 511;
  const int xcd = r & 7, loc = r >> 3;
  const int m0 = (xcd * 8 + (loc & 7)) * 128;
  const int n0 = (loc >> 3) * 128;
  const float* A = seg == 0 ? Xq : seg == 1 ? Xk : Xv;
  const u16* Bw = seg == 0 ? Wq : seg == 1 ? Wk : Wv;
  const float* bias = seg == 0 ? bq : seg == 1 ? bk : bv;
  u16* C = seg == 0 ? Cq : seg == 1 ? Ck : Cv;
  const float scale = seg == 0 ? SCQ : 1.0f;
  gemm_body32<true>(A, Bw, bias, C, m0, n0, As, Bs, scale);
}

// ---------------- fused causal attention with relative-position bias ----------------
// 2048 blocks x 256 threads (4 waves), UNPAIRED heavy-first (qi = 15..0 per
// XCD). NO pos ring: per tile the 6 pos fragments are loaded straight from
// L2-hot posB into registers (issued before KV(t+1); QK covers their latency;
// vmcnt(2) before REL keeps KV(t+1) in flight). LDS 21.25 KB -> residency
// bounded by VGPR (~5 blocks/CU = 20 waves). ONE barrier per tile.
__global__ __launch_bounds__(256) void attn_kernel(const u16* __restrict__ Q,
                                                   const u16* __restrict__ Kb,
                                                   const u16* __restrict__ Vb,
                                                   const u16* __restrict__ posB,
                                                   u16* __restrict__ O) {
  __shared__ u16 Ks[2][KV * 64];   // K tiles, XOR-swizzled 16B granules
  __shared__ u16 Vs[2][KV * 64];   // V tiles subtiled [j>>2][d>>4][j&3][d&15]
  __shared__ u16 SH[4][16 * 40];   // per-wave: bias-by-col / P tile, stride 40

  const int tid = threadIdx.x;
  const int wave = tid >> 6, lane = tid & 63;
  const int lr = lane & 15, lg = lane >> 4;
  // XCD-clustered: each XCD owns 16 (b,h) pairs; heavy q-chunks launch first.
  const int bid = blockIdx.x;
  const int xcd = bid & 7;
  const int idx = bid >> 3;        // 0..255
  const int bhl = idx & 15;
  const int qi  = 15 - (idx >> 4); // 15..0, heavy first
  const int bh  = xcd * 16 + bhl;
  const int b = bh >> 4, h = bh & 15;
  const int qb = qi * 64;
  const int wq = qb + wave * 16;
  const int nt = 2 * qi + 2;
  const int qg = wq + lr;

  u16* SHW = SH[wave];
  const size_t rowbase = (size_t)(b * Sz) * Dm + h * HDm;

  // staging source indices (one 16B chunk per thread per item)
  const int krow = tid >> 3, kc = tid & 7;             // K: row-major swizzled
  const int vj = ((tid >> 5) << 2) | ((tid >> 1) & 3); // V: subtile layout
  const int vd = ((tid >> 3) & 3) * 16 + (tid & 1) * 8;

  auto issueKV = [&](int t) {
    const int j0 = t * KV;
    const int bsel = t & 1;
    gload(Kb + rowbase + (size_t)(j0 + krow) * Dm + ((kc ^ (krow & 7)) * 8),
          &Ks[bsel][wave * 512]);
    gload(Vb + rowbase + (size_t)(j0 + vj) * Dm + vd, &Vs[bsel][wave * 512]);
  };

  const u16* qptr = Q + rowbase + (size_t)(wq + lr) * Dm;
  bf16x8 qf[2];
  qf[0] = *(const bf16x8*)(qptr + lg * 8);
  qf[1] = *(const bf16x8*)(qptr + 32 + lg * 8);

  // per-lane scalar bias for fully-clamped tiles: q_row . pos[511]
  float b511;
  {
    const u16* pp = posB + (NREL - 1) * HDm;
    bf16x8 pa0 = *(const bf16x8*)(pp + lg * 8);
    bf16x8 pa1 = *(const bf16x8*)(pp + 32 + lg * 8);
    f32x4 a = {};
    a = mfma16(pa0, qf[0], a);
    a = mfma16(pa1, qf[1], a);
    b511 = a[0];
  }

  issueKV(0);

  f32x4 oacc[4] = {};
  float m_i = -1e30f, l_i = 0.f;
  bf16x8 P[6];  // this tile's pos fragments (B-operand for REL)

  for (int t = 0; t < nt; ++t) {
    const int j0 = t * KV;
    const int bsel = t & 1;
    const bool active = (j0 <= wq + 15);
    const bool clamp = (wq - j0 - 31) >= NREL - 1;  // whole tile rel>=511
    const int wb = wq - j0 - 31;

    __builtin_amdgcn_s_barrier();
    // pos(t) register loads FIRST (so REL's wait leaves KV(t+1) flying)
    #pragma unroll
    for (int wg = 0; wg < 3; ++wg) {
      int prow = wb + wg * 16 + lr;
      prow = prow < 0 ? 0 : (prow > NREL - 1 ? NREL - 1 : prow);
      const u16* pp = posB + prow * HDm;
      P[2 * wg]     = *(const bf16x8*)(pp + lg * 8);
      P[2 * wg + 1] = *(const bf16x8*)(pp + 32 + lg * 8);
    }
    __builtin_amdgcn_sched_barrier(0);
    if (t + 1 < nt) {
      issueKV(t + 1);
      __builtin_amdgcn_sched_barrier(0);
      asm volatile("s_waitcnt vmcnt(8)" ::: "memory");  // KV(t) landed
    } else {
      asm volatile("s_waitcnt vmcnt(6)" ::: "memory");  // KV(t) landed
    }

    if (active) {
      // ---- swapped QK^T first (covers pos loads' L2 latency) ----
      __builtin_amdgcn_s_setprio(1);
      f32x4 s0 = {}, s1 = {};
      const u16* KT = &Ks[bsel][0];
      s0 = mfma16(*(const bf16x8*)&KT[(0 + lr) * 64 + (((0 + lg) ^ (lr & 7)) * 8)], qf[0], s0);
      s0 = mfma16(*(const bf16x8*)&KT[(0 + lr) * 64 + (((4 + lg) ^ (lr & 7)) * 8)], qf[1], s0);
      s1 = mfma16(*(const bf16x8*)&KT[(16 + lr) * 64 + (((0 + lg) ^ (lr & 7)) * 8)], qf[0], s1);
      s1 = mfma16(*(const bf16x8*)&KT[(16 + lr) * 64 + (((4 + lg) ^ (lr & 7)) * 8)], qf[1], s1);
      __builtin_amdgcn_s_setprio(0);

      if (!clamp) {
        // ---- REL bias via MFMA on pos registers, stored by column ----
        if (t + 1 < nt) {
          asm volatile("s_waitcnt vmcnt(2)" ::: "memory");  // pos(t) landed
        } else {
          asm volatile("s_waitcnt vmcnt(0)" ::: "memory");
        }
        __builtin_amdgcn_sched_barrier(0);
        #pragma unroll
        for (int wg = 0; wg < 3; ++wg) {
          f32x4 a = {};
          a = mfma16(qf[0], P[2 * wg], a);
          a = mfma16(qf[1], P[2 * wg + 1], a);
          #pragma unroll
          for (int r = 0; r < 4; ++r) {
            const int q = lg * 4 + r;
            const int col = q - (wg * 16 + lr) + 31;
            if (col >= 0 && col < 32)
              SHW[q * 40 + col] = f2bf(a[r]);
          }
        }
      }

      float p0[4], p1[4];
      float tmax = -3e38f;
      if (clamp) {
        #pragma unroll
        for (int r = 0; r < 4; ++r) {
          p0[r] = s0[r] + b511; tmax = fmaxf(tmax, p0[r]);
          p1[r] = s1[r] + b511; tmax = fmaxf(tmax, p1[r]);
        }
      } else {
        u16x4 bv0 = *(const u16x4*)&SHW[lr * 40 + lg * 4];
        u16x4 bv1 = *(const u16x4*)&SHW[lr * 40 + 16 + lg * 4];
        if (j0 + 31 > wq) {
          // diagonal tile: per-element causal mask needed
          #pragma unroll
          for (int r = 0; r < 4; ++r) {
            float v0 = s0[r] + bf2f(bv0[r]);
            if (j0 + lg * 4 + r > qg) v0 = -1e9f;
            p0[r] = v0; tmax = fmaxf(tmax, v0);
            float v1 = s1[r] + bf2f(bv1[r]);
            if (j0 + 16 + lg * 4 + r > qg) v1 = -1e9f;
            p1[r] = v1; tmax = fmaxf(tmax, v1);
          }
        } else {
          // strictly-past tile: no mask
          #pragma unroll
          for (int r = 0; r < 4; ++r) {
            p0[r] = s0[r] + bf2f(bv0[r]); tmax = fmaxf(tmax, p0[r]);
            p1[r] = s1[r] + bf2f(bv1[r]); tmax = fmaxf(tmax, p1[r]);
          }
        }
      }
      tmax = fmaxf(tmax, __shfl_xor(tmax, 16));
      tmax = fmaxf(tmax, __shfl_xor(tmax, 32));

      // defer-max (base-2 units: 11.5 ~ e^8)
      if (!__all(tmax <= m_i + 11.5f)) {
        float mn = fmaxf(m_i, tmax);
        float sc = ex2(m_i - mn);
        m_i = mn; l_i *= sc;
        #pragma unroll
        for (int dg = 0; dg < 4; ++dg) oacc[dg] *= sc;
      }

      float lsum = 0.f;
      #pragma unroll
      for (int r = 0; r < 4; ++r) {
        p0[r] = ex2(p0[r] - m_i); lsum += p0[r];
        p1[r] = ex2(p1[r] - m_i); lsum += p1[r];
      }
      lsum += __shfl_xor(lsum, 16);
      lsum += __shfl_xor(lsum, 32);
      l_i += lsum;

      // ---- P pack -> own q-row slots (overwrites bias) ----
      u16x4 pk0, pk1;
      #pragma unroll
      for (int r = 0; r < 4; ++r) { pk0[r] = f2bf(p0[r]); pk1[r] = f2bf(p1[r]); }
      *(u16x4*)&SHW[lr * 40 + lg * 4] = pk0;
      *(u16x4*)&SHW[lr * 40 + 16 + lg * 4] = pk1;

      bf16x8 pB = *(const bf16x8*)&SHW[lr * 40 + lg * 8];

      // ---- PV: O^T = V^T x P via tr-read V fragments as A-operand ----
      u16x4 va[4][2];
      #pragma unroll
      for (int dg = 0; dg < 4; ++dg) {
        const u16* base = &Vs[bsel][(2 * lg) * 256 + dg * 64 + lr * 4];
        va[dg][0] = tr0(base);
        va[dg][1] = tr512(base);
      }
      asm volatile("s_waitcnt lgkmcnt(0)" ::: "memory");
      __builtin_amdgcn_sched_barrier(0);
      __builtin_amdgcn_s_setprio(1);
      #pragma unroll
      for (int dg = 0; dg < 4; ++dg)
        oacc[dg] = mfma16(mk8(va[dg][0], va[dg][1]), pB, oacc[dg]);
      __builtin_amdgcn_s_setprio(0);
    }
  }

  // epilogue: lane holds O^T[d = dg*16+lg*4+r][q = qg]; 4 x 8B stores
  const float inv = 1.0f / l_i;
  const size_t obase = rowbase + (size_t)qg * Dm;
  #pragma unroll
  for (int dg = 0; dg < 4; ++dg) {
    u16x4 w;
    #pragma unroll
    for (int r = 0; r < 4; ++r) w[r] = f2bf(oacc[dg][r] * inv);
    *(u16x4*)&O[obase + dg * 16 + lg * 4] = w;
  }
}

// ---------------- launcher ----------------
extern "C" void kernel_launch(void* const* d_in, const int* in_sizes, int n_in,
                              void* d_out, int out_size, void* d_ws, size_t ws_size,
                              hipStream_t stream) {
  const float* query = (const float*)d_in[0];
  const float* key   = (const float*)d_in[1];
  const float* value = (const float*)d_in[2];
  const float* Wq    = (const float*)d_in[3];
  const float* bq    = (const float*)d_in[4];
  const float* Wk    = (const float*)d_in[5];
  const float* bk    = (const float*)d_in[6];
  const float* Wv    = (const float*)d_in[7];
  const float* bv    = (const float*)d_in[8];
  const float* Wo    = (const float*)d_in[9];
  const float* bo    = (const float*)d_in[10];
  const float* pos   = (const float*)d_in[11];

  char* ws = (char*)d_ws;
  u16* WqB  = (u16*)(ws);                 // 2 MB
  u16* WkB  = (u16*)(ws + (2ull << 20));  // 2 MB
  u16* WvB  = (u16*)(ws + (4ull << 20));  // 2 MB
  u16* WoB  = (u16*)(ws + (6ull << 20));  // 2 MB
  u16* posB = (u16*)(ws + (8ull << 20));  // 64 KB
  u16* Qb   = (u16*)(ws + (9ull << 20));  // 16 MB
  u16* Kb   = (u16*)(ws + (25ull << 20)); // 16 MB
  u16* Vb   = (u16*)(ws + (41ull << 20)); // 16 MB
  u16* Ob   = (u16*)(ws + (57ull << 20)); // 16 MB

  // weights + pos -> bf16, one dispatch
  cvtw_kernel<<<4128, 256, 0, stream>>>(Wq, Wk, Wv, Wo, pos,
                                        WqB, WkB, WvB, WoB, posB);

  // Q/K/V projections: fp32 inputs, fused convert in A-staging, one dispatch
  gemm3_kernel<<<1536, 256, 0, stream>>>(query, key, value, WqB, WkB, WvB,
                                         bq, bk, bv, Qb, Kb, Vb);

  attn_kernel<<<2048, 256, 0, stream>>>(Qb, Kb, Vb, posB, Ob);

  gemm1_kernel<false><<<512, 256, 0, stream>>>(Ob, WoB, bo, d_out);
}

// Round 20
// 174.131 us; speedup vs baseline: 1.2238x; 1.2238x over previous
//
#include <hip/hip_runtime.h>
#include <stdint.h>

#define DEV __device__ __forceinline__

typedef unsigned short u16;
typedef __bf16 bf16x8 __attribute__((ext_vector_type(8)));
typedef float  f32x4  __attribute__((ext_vector_type(4)));
typedef unsigned short u16x8 __attribute__((ext_vector_type(8)));
typedef unsigned short u16x4 __attribute__((ext_vector_type(4)));
typedef float  fvec4  __attribute__((ext_vector_type(4)));

constexpr int Sz   = 1024;  // sequence length
constexpr int Dm   = 1024;  // model dim
constexpr int HDm  = 64;    // head size
constexpr int NREL = 512;
constexpr int Mrows = 8192; // B*S
constexpr int KV   = 32;    // KV tile rows
constexpr float SCQ = 0.125f * 1.44269504f;  // folded into Q projection

DEV u16 f2bf(float f) { return __builtin_bit_cast(u16, (__bf16)f); }
DEV float bf2f(u16 h) { return __builtin_bit_cast(float, (uint32_t)h << 16); }
DEV f32x4 mfma16(bf16x8 a, bf16x8 b, f32x4 c) {
  return __builtin_amdgcn_mfma_f32_16x16x32_bf16(a, b, c, 0, 0, 0);
}
DEV float ex2(float x) {  // v_exp_f32 computes 2^x
  float r;
  asm("v_exp_f32 %0, %1" : "=v"(r) : "v"(x));
  return r;
}

// hardware transpose read. Lane l fetches 8B at its OWN addr; fixed cross-lane
// permute within each 16-lane group delivers elem j = region[(l&15) + 16j].
DEV u16x4 tr0(const u16* p) {
  u16x4 d;
  asm volatile("ds_read_b64_tr_b16 %0, %1"
               : "=v"(d)
               : "v"((const __attribute__((address_space(3))) u16*)p));
  return d;
}
DEV u16x4 tr512(const u16* p) {  // +512 bytes = next 4-row (j) subtile
  u16x4 d;
  asm volatile("ds_read_b64_tr_b16 %0, %1 offset:512"
               : "=v"(d)
               : "v"((const __attribute__((address_space(3))) u16*)p));
  return d;
}
DEV bf16x8 mk8(u16x4 a, u16x4 b) {
  u16x8 r;
  r[0] = a[0]; r[1] = a[1]; r[2] = a[2]; r[3] = a[3];
  r[4] = b[0]; r[5] = b[1]; r[6] = b[2]; r[7] = b[3];
  return __builtin_bit_cast(bf16x8, r);
}
DEV void gload(const u16* src, u16* dst) {
  __builtin_amdgcn_global_load_lds(
      (const __attribute__((address_space(1))) void*)src,
      (__attribute__((address_space(3))) void*)dst, 16, 0, 0);
}

// ---------------- merged weight/pos fp32 -> bf16 conversion ----------------
__global__ __launch_bounds__(256) void cvtw_kernel(const float* __restrict__ w0,
                                                   const float* __restrict__ w1,
                                                   const float* __restrict__ w2,
                                                   const float* __restrict__ w3,
                                                   const float* __restrict__ ps,
                                                   u16* __restrict__ o0,
                                                   u16* __restrict__ o1,
                                                   u16* __restrict__ o2,
                                                   u16* __restrict__ o3,
                                                   u16* __restrict__ op) {
  const int bid = blockIdx.x;
  const float* in;
  u16* out;
  int local;
  if (bid < 4096) {
    const int s = bid >> 10;
    in = s == 0 ? w0 : s == 1 ? w1 : s == 2 ? w2 : w3;
    out = s == 0 ? o0 : s == 1 ? o1 : s == 2 ? o2 : o3;
    local = bid & 1023;
  } else {
    in = ps; out = op; local = bid - 4096;
  }
  size_t i = (size_t)local * 256 + threadIdx.x;
  fvec4 v = *(const fvec4*)(in + i * 4);
  u16x4 o;
  o[0] = f2bf(v[0]); o[1] = f2bf(v[1]); o[2] = f2bf(v[2]); o[3] = f2bf(v[3]);
  *(u16x4*)(out + i * 4) = o;
}

// ---------------- GEMM bodies: C[m,n] = scale*(sum_k A*Bw + bias) ----------
template<bool OUT_BF16>
DEV void gemm_epilogue(const float* bias, void* Cout, int m0, int n0,
                       int wr, int wc, int lr, int lg, f32x4 acc[4][4],
                       float scale) {
  #pragma unroll
  for (int m = 0; m < 4; ++m) {
    const int grow = m0 + wr + m * 16 + lr;
    #pragma unroll
    for (int n = 0; n < 4; ++n) {
      const int gcol = n0 + wc + n * 16 + lg * 4;
      fvec4 bb = *(const fvec4*)&bias[gcol];
      if (OUT_BF16) {
        u16x4 w;
        #pragma unroll
        for (int r = 0; r < 4; ++r) w[r] = f2bf((acc[m][n][r] + bb[r]) * scale);
        *(u16x4*)&((u16*)Cout)[(size_t)grow * Dm + gcol] = w;
      } else {
        fvec4 w;
        #pragma unroll
        for (int r = 0; r < 4; ++r) w[r] = (acc[m][n][r] + bb[r]) * scale;
        *(fvec4*)&((float*)Cout)[(size_t)grow * Dm + gcol] = w;
      }
    }
  }
}

DEV void gemm_compute(const u16* Ab, const u16* Bb, int wr, int wc,
                      int lr, int lg, f32x4 (&acc)[4][4]) {
  #pragma unroll
  for (int kk = 0; kk < 2; ++kk) {
    bf16x8 af[4], bf_[4];
    #pragma unroll
    for (int m = 0; m < 4; ++m)
      af[m] = *(const bf16x8*)&Ab[(wr + m * 16 + lr) * 64 + (((kk * 4 + lg) ^ (lr & 7)) * 8)];
    #pragma unroll
    for (int n = 0; n < 4; ++n)
      bf_[n] = *(const bf16x8*)&Bb[(wc + n * 16 + lr) * 64 + (((kk * 4 + lg) ^ (lr & 7)) * 8)];
    __builtin_amdgcn_s_setprio(1);
    #pragma unroll
    for (int m = 0; m < 4; ++m)
      #pragma unroll
      for (int n = 0; n < 4; ++n)
        acc[m][n] = mfma16(bf_[n], af[m], acc[m][n]);  // swapped roles
    __builtin_amdgcn_s_setprio(0);
  }
}

// bf16-A body: both operands via global_load_lds, ONE barrier per tile.
template<bool OUT_BF16>
DEV void gemm_body16(const u16* __restrict__ A, const u16* __restrict__ Bw,
                     const float* __restrict__ bias, void* __restrict__ Cout,
                     int m0, int n0, u16* As, u16* Bs) {
  const int tid = threadIdx.x;
  const int wave = tid >> 6, lane = tid & 63;
  const int lr = lane & 15, lg = lane >> 4;
  const int wr = (wave >> 1) * 64, wc = (wave & 1) * 64;

  auto issue = [&](int t) {
    const int k0 = t * 64;
    u16* Ad = As + (t & 1) * (128 * 64);
    u16* Bd = Bs + (t & 1) * (128 * 64);
    #pragma unroll
    for (int it = 0; it < 4; ++it) {
      int chunk = it * 256 + tid;
      int row = chunk >> 3, c16 = chunk & 7;
      gload(Bw + (size_t)(n0 + row) * Dm + k0 + ((c16 ^ (row & 7)) * 8),
            Bd + (it * 256 + wave * 64) * 8);
      gload(A + (size_t)(m0 + row) * Dm + k0 + ((c16 ^ (row & 7)) * 8),
            Ad + (it * 256 + wave * 64) * 8);
    }
  };

  issue(0);
  f32x4 acc[4][4] = {};
  for (int t = 0; t < 16; ++t) {
    __builtin_amdgcn_s_barrier();
    if (t < 15) {
      issue(t + 1);
      asm volatile("s_waitcnt vmcnt(8)" ::: "memory");
    } else {
      asm volatile("s_waitcnt vmcnt(0)" ::: "memory");
    }
    gemm_compute(As + (t & 1) * (128 * 64), Bs + (t & 1) * (128 * 64),
                 wr, wc, lr, lg, acc);
  }
  gemm_epilogue<OUT_BF16>(bias, Cout, m0, n0, wr, wc, lr, lg, acc, 1.0f);
}

// fp32-A body (round-17 proven): 48 KB LDS. A reg-staged 2-deep into SINGLE-
// buffered 16 KB A-LDS; B gload_lds DOUBLE-buffered 32 KB, 1-deep prefetch.
// Head-wait vmcnt(8) drains {A(t), B(t)} while A(t+2)'s 8 stay in flight.
template<bool OUT_BF16>
DEV void gemm_body32(const float* __restrict__ A, const u16* __restrict__ Bw,
                     const float* __restrict__ bias, void* __restrict__ Cout,
                     int m0, int n0, u16* As, u16* Bs, float scale) {
  const int tid = threadIdx.x;
  const int wave = tid >> 6, lane = tid & 63;
  const int lr = lane & 15, lg = lane >> 4;
  const int wr = (wave >> 1) * 64, wc = (wave & 1) * 64;

  auto loadA = [&](int t, fvec4 (&arr)[4][2]) {
    const int k0 = t * 64;
    #pragma unroll
    for (int it = 0; it < 4; ++it) {
      int chunk = it * 256 + tid;
      int rw = chunk >> 3, cc = chunk & 7;
      const float* src = A + (size_t)(m0 + rw) * Dm + k0 + cc * 8;
      arr[it][0] = *(const fvec4*)src;
      arr[it][1] = *(const fvec4*)(src + 4);
    }
  };
  auto issueB = [&](int t) {
    const int k0 = t * 64;
    u16* Bd = Bs + (t & 1) * (128 * 64);
    #pragma unroll
    for (int it = 0; it < 4; ++it) {
      int chunk = it * 256 + tid;
      int rw = chunk >> 3, cc = chunk & 7;
      gload(Bw + (size_t)(n0 + rw) * Dm + k0 + ((cc ^ (rw & 7)) * 8),
            Bd + (it * 256 + wave * 64) * 8);
    }
  };
  auto writeA = [&](fvec4 (&arr)[4][2]) {
    #pragma unroll
    for (int it = 0; it < 4; ++it) {
      int chunk = it * 256 + tid;
      int rw = chunk >> 3, cc = chunk & 7;
      u16x8 v;
      #pragma unroll
      for (int e = 0; e < 4; ++e) { v[e] = f2bf(arr[it][0][e]); v[e + 4] = f2bf(arr[it][1][e]); }
      *(u16x8*)&As[rw * 64 + ((cc ^ (rw & 7)) * 8)] = v;
    }
  };

  fvec4 ar0[4][2], ar1[4][2];
  loadA(0, ar0);
  __builtin_amdgcn_sched_barrier(0);
  issueB(0);
  __builtin_amdgcn_sched_barrier(0);
  loadA(1, ar1);
  __builtin_amdgcn_sched_barrier(0);

  f32x4 acc[4][4] = {};
  auto step = [&](int t, fvec4 (&arr)[4][2]) {
    // head: drain {A(t), B(t)}; A(t+1) (8 ops) stays in flight
    if (t < 15) {
      asm volatile("s_waitcnt vmcnt(8)" ::: "memory");
    } else {
      asm volatile("s_waitcnt vmcnt(0)" ::: "memory");
    }
    __builtin_amdgcn_sched_barrier(0);
    writeA(arr);  // A(t) -> single-buffer LDS (post-barrier2(t-1): race-free)
    __builtin_amdgcn_sched_barrier(0);
    if (t < 15) {
      issueB(t + 1);                      // B first (order matters for vmcnt)
      __builtin_amdgcn_sched_barrier(0);
    }
    if (t < 14) {
      loadA(t + 2, arr);                  // reuse same named set (parity)
      __builtin_amdgcn_sched_barrier(0);
    }
    asm volatile("s_waitcnt lgkmcnt(0)" ::: "memory");   // A ds_writes done
    __builtin_amdgcn_s_barrier();
    gemm_compute(As, Bs + (t & 1) * (128 * 64), wr, wc, lr, lg, acc);
    __builtin_amdgcn_s_barrier();
  };
  for (int t = 0; t < 16; t += 2) {
    step(t, ar0);
    step(t + 1, ar1);
  }
  gemm_epilogue<OUT_BF16>(bias, Cout, m0, n0, wr, wc, lr, lg, acc, scale);
}

// output projection GEMM (bf16 A), XCD m-panel clustering.
template<bool OUT_BF16>
__global__ __launch_bounds__(256) void gemm1_kernel(const u16* __restrict__ A,
                                                    const u16* __restrict__ Bw,
                                                    const float* __restrict__ bias,
                                                    void* __restrict__ Cout) {
  __shared__ u16 As[2 * 128 * 64];
  __shared__ u16 Bs[2 * 128 * 64];
  const int r = blockIdx.x;
  const int xcd = r & 7, loc = r >> 3;
  const int m0 = (xcd * 8 + (loc & 7)) * 128;
  const int n0 = (loc >> 3) * 128;
  gemm_body16<OUT_BF16>(A, Bw, bias, Cout, m0, n0, As, Bs);
}

// merged Q/K/V projections, fp32 inputs with fused convert (one dispatch).
// Q (seg 0) is pre-scaled by SCQ -> attn softmax needs no mul.
__global__ __launch_bounds__(256) void gemm3_kernel(
    const float* __restrict__ Xq, const float* __restrict__ Xk, const float* __restrict__ Xv,
    const u16* __restrict__ Wq, const u16* __restrict__ Wk, const u16* __restrict__ Wv,
    const float* __restrict__ bq, const float* __restrict__ bk, const float* __restrict__ bv,
    u16* __restrict__ Cq, u16* __restrict__ Ck, u16* __restrict__ Cv) {
  __shared__ u16 As[128 * 64];
  __shared__ u16 Bs[2 * 128 * 64];
  const int flat = blockIdx.x;
  const int seg = flat >> 9;
  const int r = flat & 511;
  const int xcd = r & 7, loc = r >> 3;
  const int m0 = (xcd * 8 + (loc & 7)) * 128;
  const int n0 = (loc >> 3) * 128;
  const float* A = seg == 0 ? Xq : seg == 1 ? Xk : Xv;
  const u16* Bw = seg == 0 ? Wq : seg == 1 ? Wk : Wv;
  const float* bias = seg == 0 ? bq : seg == 1 ? bk : bv;
  u16* C = seg == 0 ? Cq : seg == 1 ? Ck : Cv;
  const float scale = seg == 0 ? SCQ : 1.0f;
  gemm_body32<true>(A, Bw, bias, C, m0, n0, As, Bs, scale);
}

// ---------------- fused causal attention with relative-position bias ----------------
// 1024 blocks x 256 threads (4 waves); PAIRED jobs (qi, 15-p) -> uniform 34
// tiles/block; pos ring in LDS; ONE barrier per tile; job-boundary barrier.
__global__ __launch_bounds__(256, 4) void attn_kernel(const u16* __restrict__ Q,
                                                      const u16* __restrict__ Kb,
                                                      const u16* __restrict__ Vb,
                                                      const u16* __restrict__ posB,
                                                      u16* __restrict__ O) {
  __shared__ u16 Ks[2][KV * 64];   // K tiles, XOR-swizzled 16B granules
  __shared__ u16 Vs[2][KV * 64];   // V tiles subtiled [j>>2][d>>4][j&3][d&15]
  __shared__ u16 ring[128 * 64];   // pos rows, slot = rel & 127, swizzle key slot&7
  __shared__ u16 SH[4][16 * 40];   // per-wave: bias-by-col / P tile, stride 40

  const int tid = threadIdx.x;
  const int wave = tid >> 6, lane = tid & 63;
  const int lr = lane & 15, lg = lane >> 4;
  // XCD-clustered: each XCD owns 16 (b,h) pairs (4 MB K/V = one L2).
  const int bid = blockIdx.x;
  const int xcd = bid & 7;
  const int idx = bid >> 3;        // 0..127
  const int bhl = idx & 15;
  const int pp_ = idx >> 4;        // pair id 0..7 -> jobs (15-p, p)
  const int bh  = xcd * 16 + bhl;
  const int b = bh >> 4, h = bh & 15;

  u16* SHW = SH[wave];
  const size_t rowbase = (size_t)(b * Sz) * Dm + h * HDm;

  // staging source indices (one 16B chunk per thread per item)
  const int krow = tid >> 3, kc = tid & 7;             // K: row-major swizzled
  const int vj = ((tid >> 5) << 2) | ((tid >> 1) & 3); // V: subtile layout
  const int vd = ((tid >> 3) & 3) * 16 + (tid & 1) * 8;
  const int rrow = tid >> 3, rcol = tid & 7;           // ring: 32 rows/chunk

  auto issueKV = [&](int t) {
    const int j0 = t * KV;
    const int bsel = t & 1;
    gload(Kb + rowbase + (size_t)(j0 + krow) * Dm + ((kc ^ (krow & 7)) * 8),
          &Ks[bsel][wave * 512]);
    gload(Vb + rowbase + (size_t)(j0 + vj) * Dm + vd, &Vs[bsel][wave * 512]);
  };
  auto stageRing = [&](int cb) {  // cb = chunk base rel (multiple of 32)
    const int rel = cb + rrow;
    const int slot = rel & 127;
    const int cl = rel < 0 ? 0 : (rel > NREL - 1 ? NREL - 1 : rel);
    gload(posB + cl * 64 + ((rcol ^ (slot & 7)) * 8),
          &ring[((cb & 127) + wave * 8) * 64]);
  };

  for (int job = 0; job < 2; ++job) {
    const int qi = job ? pp_ : 15 - pp_;     // heavy job first
    const int qb = qi * 64;
    const int wq = qb + wave * 16;
    const int nt = 2 * qi + 2;
    const int qg = wq + lr;

    const u16* qptr = Q + rowbase + (size_t)(wq + lr) * Dm;
    bf16x8 qf[2];
    qf[0] = *(const bf16x8*)(qptr + lg * 8);
    qf[1] = *(const bf16x8*)(qptr + 32 + lg * 8);

    // per-lane scalar bias for fully-clamped tiles: q_row . pos[511]
    float b511;
    {
      const u16* pp = posB + (NREL - 1) * HDm;
      bf16x8 pa0 = *(const bf16x8*)(pp + lg * 8);
      bf16x8 pa1 = *(const bf16x8*)(pp + 32 + lg * 8);
      f32x4 a = {};
      a = mfma16(pa0, qf[0], a);
      a = mfma16(pa1, qf[1], a);
      b511 = a[0];
    }

    // job boundary: all waves done reading previous job's buffers
    __builtin_amdgcn_s_barrier();
    stageRing(qb + 32);
    stageRing(qb);
    stageRing(qb - 32);
    issueKV(0);

    f32x4 oacc[4] = {};
    float m_i = -1e30f, l_i = 0.f;

    for (int t = 0; t < nt; ++t) {
      const int j0 = t * KV;
      const int bsel = t & 1;
      const bool active = (j0 <= wq + 15);
      const bool clamp = (wq - j0 - 31) >= NREL - 1;  // whole tile rel>=511
      const int wb = wq - j0 - 31;

      __builtin_amdgcn_s_barrier();
      if (t + 1 < nt) {
        stageRing(qb - 32 * (t + 1) - 32);
        issueKV(t + 1);
        asm volatile("s_waitcnt vmcnt(3)" ::: "memory");
      } else {
        asm volatile("s_waitcnt vmcnt(0)" ::: "memory");
      }

      if (active) {
        if (!clamp) {
          // ---- REL bias via MFMA from the pos ring, stored by column ----
          #pragma unroll
          for (int wg = 0; wg < 3; ++wg) {
            const int rrel = wb + wg * 16 + lr;
            const int slot = rrel & 127;
            const u16* rp = &ring[slot * 64];
            f32x4 a = {};
            a = mfma16(qf[0], *(const bf16x8*)&rp[((0 + lg) ^ (slot & 7)) * 8], a);
            a = mfma16(qf[1], *(const bf16x8*)&rp[((4 + lg) ^ (slot & 7)) * 8], a);
            #pragma unroll
            for (int r = 0; r < 4; ++r) {
              const int q = lg * 4 + r;
              const int col = q - (wg * 16 + lr) + 31;
              if (col >= 0 && col < 32)
                SHW[q * 40 + col] = f2bf(a[r]);
            }
          }
        }

        // ---- swapped QK^T: lane owns q=qg ----
        __builtin_amdgcn_s_setprio(1);
        f32x4 s0 = {}, s1 = {};
        const u16* KT = &Ks[bsel][0];
        s0 = mfma16(*(const bf16x8*)&KT[(0 + lr) * 64 + (((0 + lg) ^ (lr & 7)) * 8)], qf[0], s0);
        s0 = mfma16(*(const bf16x8*)&KT[(0 + lr) * 64 + (((4 + lg) ^ (lr & 7)) * 8)], qf[1], s0);
        s1 = mfma16(*(const bf16x8*)&KT[(16 + lr) * 64 + (((0 + lg) ^ (lr & 7)) * 8)], qf[0], s1);
        s1 = mfma16(*(const bf16x8*)&KT[(16 + lr) * 64 + (((4 + lg) ^ (lr & 7)) * 8)], qf[1], s1);
        __builtin_amdgcn_s_setprio(0);

        float p0[4], p1[4];
        float tmax = -3e38f;
        if (clamp) {
          #pragma unroll
          for (int r = 0; r < 4; ++r) {
            p0[r] = s0[r] + b511; tmax = fmaxf(tmax, p0[r]);
            p1[r] = s1[r] + b511; tmax = fmaxf(tmax, p1[r]);
          }
        } else {
          u16x4 bv0 = *(const u16x4*)&SHW[lr * 40 + lg * 4];
          u16x4 bv1 = *(const u16x4*)&SHW[lr * 40 + 16 + lg * 4];
          if (j0 + 31 > wq) {
            // diagonal tile: per-element causal mask needed
            #pragma unroll
            for (int r = 0; r < 4; ++r) {
              float v0 = s0[r] + bf2f(bv0[r]);
              if (j0 + lg * 4 + r > qg) v0 = -1e9f;
              p0[r] = v0; tmax = fmaxf(tmax, v0);
              float v1 = s1[r] + bf2f(bv1[r]);
              if (j0 + 16 + lg * 4 + r > qg) v1 = -1e9f;
              p1[r] = v1; tmax = fmaxf(tmax, v1);
            }
          } else {
            // strictly-past tile: no mask
            #pragma unroll
            for (int r = 0; r < 4; ++r) {
              p0[r] = s0[r] + bf2f(bv0[r]); tmax = fmaxf(tmax, p0[r]);
              p1[r] = s1[r] + bf2f(bv1[r]); tmax = fmaxf(tmax, p1[r]);
            }
          }
        }
        tmax = fmaxf(tmax, __shfl_xor(tmax, 16));
        tmax = fmaxf(tmax, __shfl_xor(tmax, 32));

        // defer-max (base-2 units: 11.5 ~ e^8)
        if (!__all(tmax <= m_i + 11.5f)) {
          float mn = fmaxf(m_i, tmax);
          float sc = ex2(m_i - mn);
          m_i = mn; l_i *= sc;
          #pragma unroll
          for (int dg = 0; dg < 4; ++dg) oacc[dg] *= sc;
        }

        float lsum = 0.f;
        #pragma unroll
        for (int r = 0; r < 4; ++r) {
          p0[r] = ex2(p0[r] - m_i); lsum += p0[r];
          p1[r] = ex2(p1[r] - m_i); lsum += p1[r];
        }
        lsum += __shfl_xor(lsum, 16);
        lsum += __shfl_xor(lsum, 32);
        l_i += lsum;

        // ---- P pack -> own q-row slots (overwrites bias) ----
        u16x4 pk0, pk1;
        #pragma unroll
        for (int r = 0; r < 4; ++r) { pk0[r] = f2bf(p0[r]); pk1[r] = f2bf(p1[r]); }
        *(u16x4*)&SHW[lr * 40 + lg * 4] = pk0;
        *(u16x4*)&SHW[lr * 40 + 16 + lg * 4] = pk1;

        bf16x8 pB = *(const bf16x8*)&SHW[lr * 40 + lg * 8];

        // ---- PV: O^T = V^T x P via tr-read V fragments as A-operand ----
        u16x4 va[4][2];
        #pragma unroll
        for (int dg = 0; dg < 4; ++dg) {
          const u16* base = &Vs[bsel][(2 * lg) * 256 + dg * 64 + lr * 4];
          va[dg][0] = tr0(base);
          va[dg][1] = tr512(base);
        }
        asm volatile("s_waitcnt lgkmcnt(0)" ::: "memory");
        __builtin_amdgcn_sched_barrier(0);
        __builtin_amdgcn_s_setprio(1);
        #pragma unroll
        for (int dg = 0; dg < 4; ++dg)
          oacc[dg] = mfma16(mk8(va[dg][0], va[dg][1]), pB, oacc[dg]);
        __builtin_amdgcn_s_setprio(0);
      }
    }

    // epilogue: lane holds O^T[d = dg*16+lg*4+r][q = qg]; 4 x 8B stores
    const float inv = 1.0f / l_i;
    const size_t obase = rowbase + (size_t)qg * Dm;
    #pragma unroll
    for (int dg = 0; dg < 4; ++dg) {
      u16x4 w;
      #pragma unroll
      for (int r = 0; r < 4; ++r) w[r] = f2bf(oacc[dg][r] * inv);
      *(u16x4*)&O[obase + dg * 16 + lg * 4] = w;
    }
  }
}

// ---------------- launcher ----------------
extern "C" void kernel_launch(void* const* d_in, const int* in_sizes, int n_in,
                              void* d_out, int out_size, void* d_ws, size_t ws_size,
                              hipStream_t stream) {
  const float* query = (const float*)d_in[0];
  const float* key   = (const float*)d_in[1];
  const float* value = (const float*)d_in[2];
  const float* Wq    = (const float*)d_in[3];
  const float* bq    = (const float*)d_in[4];
  const float* Wk    = (const float*)d_in[5];
  const float* bk    = (const float*)d_in[6];
  const float* Wv    = (const float*)d_in[7];
  const float* bv    = (const float*)d_in[8];
  const float* Wo    = (const float*)d_in[9];
  const float* bo    = (const float*)d_in[10];
  const float* pos   = (const float*)d_in[11];

  char* ws = (char*)d_ws;
  u16* WqB  = (u16*)(ws);                 // 2 MB
  u16* WkB  = (u16*)(ws + (2ull << 20));  // 2 MB
  u16* WvB  = (u16*)(ws + (4ull << 20));  // 2 MB
  u16* WoB  = (u16*)(ws + (6ull << 20));  // 2 MB
  u16* posB = (u16*)(ws + (8ull << 20));  // 64 KB
  u16* Qb   = (u16*)(ws + (9ull << 20));  // 16 MB
  u16* Kb   = (u16*)(ws + (25ull << 20)); // 16 MB
  u16* Vb   = (u16*)(ws + (41ull << 20)); // 16 MB
  u16* Ob   = (u16*)(ws + (57ull << 20)); // 16 MB

  // weights + pos -> bf16, one dispatch
  cvtw_kernel<<<4128, 256, 0, stream>>>(Wq, Wk, Wv, Wo, pos,
                                        WqB, WkB, WvB, WoB, posB);

  // Q/K/V projections: fp32 inputs, fused convert in A-staging, one dispatch
  gemm3_kernel<<<1536, 256, 0, stream>>>(query, key, value, WqB, WkB, WvB,
                                         bq, bk, bv, Qb, Kb, Vb);

  attn_kernel<<<1024, 256, 0, stream>>>(Qb, Kb, Vb, posB, Ob);

  gemm1_kernel<false><<<512, 256, 0, stream>>>(Ob, WoB, bo, d_out);
}